// Round 1
// 1850.414 us; speedup vs baseline: 1.1874x; 1.1874x over previous
//
#include <hip/hip_runtime.h>
#include <cstdint>
#include <cstddef>

#define TOKENS 4096
#define E_ 512
#define T_ 2048
#define H_ 8
#define L_ 6
#define FF_ 2048
#define V_ 32000

typedef unsigned short u16;
typedef __attribute__((ext_vector_type(8))) short short8;
typedef __attribute__((ext_vector_type(4))) float f32x4;

__device__ __forceinline__ u16 f2b(float f) {
  union { float f; unsigned u; } x; x.f = f;
  unsigned r = x.u + 0x7fffu + ((x.u >> 16) & 1u);
  return (u16)(r >> 16);
}

// async 16B/lane global->LDS. lds ptr must be wave-uniform; HW scatters lane i to l + i*16.
__device__ __forceinline__ void gload_lds16(const void* g, void* l) {
  __builtin_amdgcn_global_load_lds((__attribute__((address_space(1))) void*)(uintptr_t)g,
                                   (__attribute__((address_space(3))) void*)l, 16, 0, 0);
}

// ---------------------------------------------------------------------------
// GEMM: C[M,N] = A[M,K](bf16) * BT[N,K](bf16)^T + bias, optional +resid / relu
// 128x128 tile, BK=32, 256 threads (4 waves, 2x2 of 64x64), m97 structure.
// ---------------------------------------------------------------------------
template<int BF16OUT, int RESID, int RELU>
__global__ __launch_bounds__(256) void gemm_bt(
    const u16* __restrict__ A, const u16* __restrict__ BT,
    const float* __restrict__ bias, const float* __restrict__ resid,
    void* __restrict__ outp, int M, int N, int K, int ldc)
{
  __shared__ u16 a_sm[128 * 32];
  __shared__ u16 b_sm[128 * 32];
  const int tid  = threadIdx.x;
  const int wave = tid >> 6;
  const int lane = tid & 63;
  const int l16  = lane & 15;
  const int quad = lane >> 4;
  const int bm = blockIdx.y << 7;
  const int bn = blockIdx.x << 7;
  const int wr = (wave >> 1) << 6;
  const int wc = (wave & 1) << 6;

  const int srow = tid >> 2;          // 0..63
  const int soff = (tid & 3) << 3;    // element offset in 32-wide K slab
  const u16* ag0 = A  + (size_t)(bm + srow) * K + soff;
  const u16* ag1 = A  + (size_t)(bm + 64 + srow) * K + soff;
  const u16* bg0 = BT + (size_t)(bn + srow) * K + soff;
  const u16* bg1 = BT + (size_t)(bn + 64 + srow) * K + soff;
  u16* al0 = a_sm + wave * 512;          // wave-uniform LDS bases
  u16* al1 = a_sm + 2048 + wave * 512;
  u16* bl0 = b_sm + wave * 512;
  u16* bl1 = b_sm + 2048 + wave * 512;

  f32x4 acc[4][4] = {};

  for (int k0 = 0; k0 < K; k0 += 32) {
    gload_lds16(ag0 + k0, al0);
    gload_lds16(ag1 + k0, al1);
    gload_lds16(bg0 + k0, bl0);
    gload_lds16(bg1 + k0, bl1);
    __syncthreads();
    short8 af[4], bf[4];
#pragma unroll
    for (int mt = 0; mt < 4; ++mt)
      af[mt] = *(const short8*)&a_sm[(wr + mt * 16 + l16) * 32 + quad * 8];
#pragma unroll
    for (int nt = 0; nt < 4; ++nt)
      bf[nt] = *(const short8*)&b_sm[(wc + nt * 16 + l16) * 32 + quad * 8];
#pragma unroll
    for (int mt = 0; mt < 4; ++mt)
#pragma unroll
      for (int nt = 0; nt < 4; ++nt)
        acc[mt][nt] = __builtin_amdgcn_mfma_f32_16x16x32_bf16(af[mt], bf[nt], acc[mt][nt], 0, 0, 0);
    __syncthreads();
  }

#pragma unroll
  for (int mt = 0; mt < 4; ++mt) {
#pragma unroll
    for (int nt = 0; nt < 4; ++nt) {
      const int cg = bn + wc + nt * 16 + l16;
      const int rg = bm + wr + mt * 16 + quad * 4;
      const float bv = bias[cg];
#pragma unroll
      for (int i = 0; i < 4; ++i) {
        float v = acc[mt][nt][i] + bv;
        size_t idx = (size_t)(rg + i) * ldc + cg;
        if (RESID) v += resid[idx];
        if (RELU)  v = fmaxf(v, 0.f);
        if (BF16OUT) ((u16*)outp)[idx] = f2b(v);
        else         ((float*)outp)[idx] = v;
      }
    }
  }
}

// ---------------------------------------------------------------------------
// Split-K GEMM partial: part[z][M][N] = A[:, z*kLen:(z+1)*kLen] * BT^T chunk.
// No bias/resid; fp32 out. lda = row stride of BOTH A and BT (= full K).
// grid (N/128, M/128, NSPLIT). Fills the machine for N=512 GEMMs.
// ---------------------------------------------------------------------------
__global__ __launch_bounds__(256) void gemm_bt_sk(
    const u16* __restrict__ A, const u16* __restrict__ BT,
    float* __restrict__ part, int M, int N, int lda, int kLen)
{
  __shared__ u16 a_sm[128 * 32];
  __shared__ u16 b_sm[128 * 32];
  const int tid  = threadIdx.x;
  const int wave = tid >> 6;
  const int lane = tid & 63;
  const int l16  = lane & 15;
  const int quad = lane >> 4;
  const int bm = blockIdx.y << 7;
  const int bn = blockIdx.x << 7;
  const int wr = (wave >> 1) << 6;
  const int wc = (wave & 1) << 6;

  const u16* Ab = A  + (size_t)blockIdx.z * kLen;
  const u16* Bb = BT + (size_t)blockIdx.z * kLen;

  const int srow = tid >> 2;
  const int soff = (tid & 3) << 3;
  const u16* ag0 = Ab + (size_t)(bm + srow) * lda + soff;
  const u16* ag1 = Ab + (size_t)(bm + 64 + srow) * lda + soff;
  const u16* bg0 = Bb + (size_t)(bn + srow) * lda + soff;
  const u16* bg1 = Bb + (size_t)(bn + 64 + srow) * lda + soff;
  u16* al0 = a_sm + wave * 512;
  u16* al1 = a_sm + 2048 + wave * 512;
  u16* bl0 = b_sm + wave * 512;
  u16* bl1 = b_sm + 2048 + wave * 512;

  f32x4 acc[4][4] = {};

  for (int k0 = 0; k0 < kLen; k0 += 32) {
    gload_lds16(ag0 + k0, al0);
    gload_lds16(ag1 + k0, al1);
    gload_lds16(bg0 + k0, bl0);
    gload_lds16(bg1 + k0, bl1);
    __syncthreads();
    short8 af[4], bf[4];
#pragma unroll
    for (int mt = 0; mt < 4; ++mt)
      af[mt] = *(const short8*)&a_sm[(wr + mt * 16 + l16) * 32 + quad * 8];
#pragma unroll
    for (int nt = 0; nt < 4; ++nt)
      bf[nt] = *(const short8*)&b_sm[(wc + nt * 16 + l16) * 32 + quad * 8];
#pragma unroll
    for (int mt = 0; mt < 4; ++mt)
#pragma unroll
      for (int nt = 0; nt < 4; ++nt)
        acc[mt][nt] = __builtin_amdgcn_mfma_f32_16x16x32_bf16(af[mt], bf[nt], acc[mt][nt], 0, 0, 0);
    __syncthreads();
  }

  float* out = part + (size_t)blockIdx.z * M * N;
#pragma unroll
  for (int mt = 0; mt < 4; ++mt) {
#pragma unroll
    for (int nt = 0; nt < 4; ++nt) {
      const int cg = bn + wc + nt * 16 + l16;
      const int rg = bm + wr + mt * 16 + quad * 4;
#pragma unroll
      for (int i = 0; i < 4; ++i)
        out[(size_t)(rg + i) * N + cg] = acc[mt][nt][i];
    }
  }
}

// ---------------------------------------------------------------------------
// Flash-style causal attention, KVBLK=64, T2 XOR-swizzled LDS.
// qkv: [TOKENS][1536] bf16 (q|k|v, head h at col h*64 in each 512 section).
// o: [TOKENS][512] bf16. grid (T/64, B*H); block 256 = 4 waves x 16 q-rows.
// LDS rows are 128B -> naive ds_read_b128 is 16-way bank-conflicted; all
// k/vT/p buffers use chunk ^= (row&7) swizzle (16B chunks). K is staged via
// global_load_lds with the INVERSE swizzle applied to the per-lane global
// source address (linear LDS dest, rule #21 / m173 pattern).
// ---------------------------------------------------------------------------
__global__ __launch_bounds__(256) void attn_kernel(const u16* __restrict__ qkv,
                                                   u16* __restrict__ o)
{
  __shared__ u16 k_sm[64 * 64];    // [key][d], swizzled
  __shared__ u16 vT_sm[64 * 64];   // [d][key], swizzled
  __shared__ u16 p_sm[4 * 16 * 64];// per-wave P [qrow][key], swizzled
  const int tid  = threadIdx.x;
  const int wave = tid >> 6;
  const int lane = tid & 63;
  const int l16  = lane & 15;
  const int quad = lane >> 4;
  const int j  = blockIdx.x;                 // q tile of 64 rows
  const int bh = blockIdx.y;
  const int b  = bh >> 3, h = bh & 7;
  const size_t base = (size_t)b * T_ * 1536;

  // Q fragments (A-layout): rows j*64 + wave*16 + l16, k = half*32 + quad*8
  const int qrow = j * 64 + wave * 16 + l16;
  short8 aq[2];
#pragma unroll
  for (int half = 0; half < 2; ++half)
    aq[half] = *(const short8*)&qkv[base + (size_t)qrow * 1536 + h * 64 + half * 32 + quad * 8];

  f32x4 oacc[4] = {};
  float m_i[4] = {-INFINITY, -INFINITY, -INFINITY, -INFINITY};
  float l_i[4] = {0.f, 0.f, 0.f, 0.f};

  // pre-swizzled global source column offset for K staging:
  // lane writes LDS row (tid>>3)&31 (+32 for 2nd call), chunk tid&7;
  // swizzled content wants global chunk (tid&7) ^ ((tid>>3)&7).
  const int ksrc = ((tid & 7) ^ ((tid >> 3) & 7)) * 8;

  const int nkt = j + 1;
  for (int kt = 0; kt < nkt; ++kt) {
    __syncthreads();  // prior tile's LDS reads done before overwrite
    // stage K tile [64][64] (two 32-row halves), swizzled via source perm
    gload_lds16(qkv + base + (size_t)(kt * 64 + (tid >> 3)) * 1536 + 512 + h * 64 + ksrc,
                k_sm + wave * 512);
    gload_lds16(qkv + base + (size_t)(kt * 64 + 32 + (tid >> 3)) * 1536 + 512 + h * 64 + ksrc,
                k_sm + 2048 + wave * 512);
    // stage V transposed: thread handles key t, d0..d0+16; swizzled writes
    {
      const int t = tid >> 2, d0 = (tid & 3) * 16;
      const u16* vp = &qkv[base + (size_t)(kt * 64 + t) * 1536 + 1024 + h * 64 + d0];
      short8 v0 = *(const short8*)vp;
      short8 v1 = *(const short8*)(vp + 8);
#pragma unroll
      for (int i = 0; i < 8; ++i) vT_sm[(d0 + i) * 64 + (t ^ (i << 3))] = (u16)v0[i];
#pragma unroll
      for (int i = 0; i < 8; ++i) vT_sm[(d0 + 8 + i) * 64 + (t ^ (i << 3))] = (u16)v1[i];
    }
    __syncthreads();

    // S = Q K^T (four 16x16 col-tiles over 64 keys)
    f32x4 s[4] = {};
#pragma unroll
    for (int nt = 0; nt < 4; ++nt)
#pragma unroll
      for (int half = 0; half < 2; ++half) {
        short8 bk = *(const short8*)&k_sm[(nt * 16 + l16) * 64 +
                                          (((half * 4 + quad) ^ (l16 & 7)) << 3)];
        s[nt] = __builtin_amdgcn_mfma_f32_16x16x32_bf16(aq[half], bk, s[nt], 0, 0, 0);
      }
    // scale + causal mask
#pragma unroll
    for (int nt = 0; nt < 4; ++nt)
#pragma unroll
      for (int i = 0; i < 4; ++i) {
        const int col = kt * 64 + nt * 16 + l16;
        const int row = j * 64 + wave * 16 + quad * 4 + i;
        float sv = s[nt][i] * 0.125f;
        s[nt][i] = (col <= row) ? sv : -INFINITY;
      }
    // online softmax: row stats across the 16 lanes of each quad
    float rm[4], mn[4], alpha[4], rs[4], p[4][4];
#pragma unroll
    for (int i = 0; i < 4; ++i)
      rm[i] = fmaxf(fmaxf(s[0][i], s[1][i]), fmaxf(s[2][i], s[3][i]));
#pragma unroll
    for (int off = 1; off < 16; off <<= 1)
#pragma unroll
      for (int i = 0; i < 4; ++i) rm[i] = fmaxf(rm[i], __shfl_xor(rm[i], off));
#pragma unroll
    for (int i = 0; i < 4; ++i) {
      mn[i] = fmaxf(m_i[i], rm[i]);
      alpha[i] = __expf(m_i[i] - mn[i]);
      m_i[i] = mn[i];
#pragma unroll
      for (int nt = 0; nt < 4; ++nt) p[nt][i] = __expf(s[nt][i] - mn[i]);
      rs[i] = (p[0][i] + p[1][i]) + (p[2][i] + p[3][i]);
    }
#pragma unroll
    for (int off = 1; off < 16; off <<= 1)
#pragma unroll
      for (int i = 0; i < 4; ++i) rs[i] += __shfl_xor(rs[i], off);
#pragma unroll
    for (int i = 0; i < 4; ++i) l_i[i] = l_i[i] * alpha[i] + rs[i];
#pragma unroll
    for (int nt = 0; nt < 4; ++nt)
#pragma unroll
      for (int i = 0; i < 4; ++i) oacc[nt][i] *= alpha[i];
    // P: C-layout -> LDS (swizzled) -> A-layout
    u16* pw = p_sm + wave * 1024;
#pragma unroll
    for (int i = 0; i < 4; ++i) {
      const int pr = quad * 4 + i;
#pragma unroll
      for (int nt = 0; nt < 4; ++nt)
        pw[pr * 64 + ((nt * 16 + l16) ^ ((pr & 7) << 3))] = f2b(p[nt][i]);
    }
    asm volatile("s_waitcnt lgkmcnt(0)" ::: "memory");
    short8 pf[2];
#pragma unroll
    for (int kh = 0; kh < 2; ++kh)
      pf[kh] = *(const short8*)&pw[l16 * 64 + (((kh * 4 + quad) ^ (l16 & 7)) << 3)];
#pragma unroll
    for (int nt = 0; nt < 4; ++nt)
#pragma unroll
      for (int kh = 0; kh < 2; ++kh) {
        short8 bv = *(const short8*)&vT_sm[(nt * 16 + l16) * 64 +
                                           (((kh * 4 + quad) ^ (l16 & 7)) << 3)];
        oacc[nt] = __builtin_amdgcn_mfma_f32_16x16x32_bf16(pf[kh], bv, oacc[nt], 0, 0, 0);
      }
  }
  // epilogue: O / l
#pragma unroll
  for (int nt = 0; nt < 4; ++nt)
#pragma unroll
    for (int i = 0; i < 4; ++i) {
      const int row = j * 64 + wave * 16 + quad * 4 + i;
      const float ov = oacc[nt][i] / l_i[i];
      o[(size_t)(b * T_ + row) * 512 + h * 64 + nt * 16 + l16] = f2b(ov);
    }
}

// ---------------------------------------------------------------------------
// Row LN helper: hv = this thread's 2 elems of a 512-row; writes bf16x2 to yrow.
// ---------------------------------------------------------------------------
__device__ __forceinline__ void ln_emit(float2 hv, const float* __restrict__ sc,
                                        const float* __restrict__ bi, int tid,
                                        unsigned* __restrict__ yrow)
{
  float s = hv.x + hv.y;
  float q = hv.x * hv.x + hv.y * hv.y;
  for (int off = 32; off; off >>= 1) { s += __shfl_down(s, off); q += __shfl_down(q, off); }
  __shared__ float red[8];
  const int wave = tid >> 6, lane = tid & 63;
  if (!lane) { red[wave] = s; red[4 + wave] = q; }
  __syncthreads();
  if (tid == 0) {
    float ts = 0, tq = 0;
    for (int w = 0; w < 4; ++w) { ts += red[w]; tq += red[4 + w]; }
    red[0] = ts; red[4] = tq;
  }
  __syncthreads();
  const float mu = red[0] * (1.f / 512.f);
  const float var = red[4] * (1.f / 512.f) - mu * mu;
  const float rstd = rsqrtf(var + 1e-5f);
  const float y0 = (hv.x - mu) * rstd * sc[tid * 2]     + bi[tid * 2];
  const float y1 = (hv.y - mu) * rstd * sc[tid * 2 + 1] + bi[tid * 2 + 1];
  yrow[tid] = ((unsigned)f2b(y1) << 16) | (unsigned)f2b(y0);
}

// ---------------------------------------------------------------------------
// Split-K reduce + residual + bias into h, fused with the NEXT op's LN (or a
// plain bf16 copy when DOLN=0). Row per block, 256 threads, float2/thread.
// ---------------------------------------------------------------------------
template<int NS, int DOLN>
__global__ __launch_bounds__(256) void resid_ln_kernel(
    const float* __restrict__ part, const float* __restrict__ bias,
    float* __restrict__ h, const float* __restrict__ sc,
    const float* __restrict__ bi, u16* __restrict__ y)
{
  const int row = blockIdx.x, tid = threadIdx.x;
  float2 hv = ((const float2*)(h + (size_t)row * 512))[tid];
  const float2 bv = ((const float2*)bias)[tid];
#pragma unroll
  for (int s = 0; s < NS; ++s) {
    const float2 pv = ((const float2*)(part + ((size_t)s * TOKENS + row) * 512))[tid];
    hv.x += pv.x; hv.y += pv.y;
  }
  hv.x += bv.x; hv.y += bv.y;
  ((float2*)(h + (size_t)row * 512))[tid] = hv;
  if (DOLN)
    ln_emit(hv, sc, bi, tid, (unsigned*)(y + (size_t)row * 512));
  else
    ((unsigned*)y)[(size_t)row * 256 + tid] = ((unsigned)f2b(hv.y) << 16) | (unsigned)f2b(hv.x);
}

// ---------------------------------------------------------------------------
// Embedding fused with ln1(layer 0): h[row] = tok_emb[x]+pos_emb, y = LN(h).
// ---------------------------------------------------------------------------
__global__ __launch_bounds__(256) void embed_ln_kernel(const int* __restrict__ x,
                                                       const float* __restrict__ tok,
                                                       const float* __restrict__ pos,
                                                       const float* __restrict__ sc,
                                                       const float* __restrict__ bi,
                                                       float* __restrict__ h,
                                                       u16* __restrict__ y)
{
  const int row = blockIdx.x, tid = threadIdx.x;
  const int t = row & (T_ - 1);
  const int tk = x[row];
  const float2 a = ((const float2*)tok)[(size_t)tk * 256 + tid];
  const float2 p = ((const float2*)pos)[(size_t)t * 256 + tid];
  float2 hv = make_float2(a.x + p.x, a.y + p.y);
  ((float2*)(h + (size_t)row * 512))[tid] = hv;
  ln_emit(hv, sc, bi, tid, (unsigned*)(y + (size_t)row * 512));
}

// ---------------------------------------------------------------------------
// Weight transpose + fp32->bf16: src [K][N] (layer stride sStr) -> dst [N][K]
// block (32,8), 32x32 tiles via padded LDS.
// ---------------------------------------------------------------------------
__global__ void transW(const float* __restrict__ src, u16* __restrict__ dst,
                       int K, int N, long sStr, long dStr)
{
  __shared__ float tile[32][33];
  const int l = blockIdx.z;
  const float* S = src + (size_t)l * sStr;
  u16* D = dst + (size_t)l * dStr;
  const int n0 = blockIdx.x * 32, k0 = blockIdx.y * 32;
  const int tx = threadIdx.x, ty = threadIdx.y;
#pragma unroll
  for (int i = 0; i < 4; ++i)
    tile[ty + 8 * i][tx] = S[(size_t)(k0 + ty + 8 * i) * N + n0 + tx];
  __syncthreads();
#pragma unroll
  for (int i = 0; i < 4; ++i)
    D[(size_t)(n0 + ty + 8 * i) * K + k0 + tx] = f2b(tile[tx][ty + 8 * i]);
}

__global__ __launch_bounds__(256) void bias_cat_kernel(const float* __restrict__ bq,
                                                       const float* __restrict__ bk,
                                                       const float* __restrict__ bv,
                                                       float* __restrict__ o)
{
  const int i = blockIdx.x * 256 + threadIdx.x;
  if (i >= L_ * 1536) return;
  const int l = i / 1536, c = i % 1536;
  float v = (c < 512) ? bq[l * 512 + c] : (c < 1024) ? bk[l * 512 + c - 512] : bv[l * 512 + c - 1024];
  o[i] = v;
}

// ---------------------------------------------------------------------------
extern "C" void kernel_launch(void* const* d_in, const int* in_sizes, int n_in,
                              void* d_out, int out_size, void* d_ws, size_t ws_size,
                              hipStream_t stream) {
  const int*   x     = (const int*)d_in[0];
  const float* tok   = (const float*)d_in[1];
  const float* pos   = (const float*)d_in[2];
  const float* Wq    = (const float*)d_in[3];
  const float* bq    = (const float*)d_in[4];
  const float* Wk    = (const float*)d_in[5];
  const float* bk    = (const float*)d_in[6];
  const float* Wv    = (const float*)d_in[7];
  const float* bv    = (const float*)d_in[8];
  const float* Wo    = (const float*)d_in[9];
  const float* bo    = (const float*)d_in[10];
  const float* ln1s  = (const float*)d_in[11];
  const float* ln1b  = (const float*)d_in[12];
  const float* ln2s  = (const float*)d_in[13];
  const float* ln2b  = (const float*)d_in[14];
  const float* W1    = (const float*)d_in[15];
  const float* b1    = (const float*)d_in[16];
  const float* W2    = (const float*)d_in[17];
  const float* b2    = (const float*)d_in[18];
  const float* Wout  = (const float*)d_in[19];
  const float* bout  = (const float*)d_in[20];

  char* ws = (char*)d_ws;
  size_t off = 0;
  auto alloc = [&](size_t bytes) { char* p = ws + off; off += (bytes + 255) & ~(size_t)255; return p; };
  u16*   qkvT  = (u16*)alloc((size_t)L_ * 1536 * 512 * 2);
  u16*   WoT   = (u16*)alloc((size_t)L_ * 512 * 512 * 2);
  u16*   W1T   = (u16*)alloc((size_t)L_ * 2048 * 512 * 2);
  u16*   W2T   = (u16*)alloc((size_t)L_ * 512 * 2048 * 2);
  u16*   WoutT = (u16*)alloc((size_t)V_ * 512 * 2);
  float* bqkv  = (float*)alloc((size_t)L_ * 1536 * 4);
  float* h     = (float*)alloc((size_t)TOKENS * 512 * 4);
  u16*   y     = (u16*)alloc((size_t)TOKENS * 512 * 2);
  u16*   qkv   = (u16*)alloc((size_t)TOKENS * 1536 * 2);
  u16*   obuf  = (u16*)alloc((size_t)TOKENS * 512 * 2);
  u16*   ff    = (u16*)alloc((size_t)TOKENS * 2048 * 2);
  u16*   hb    = (u16*)alloc((size_t)TOKENS * 512 * 2);
  float* part  = (float*)alloc((size_t)4 * TOKENS * 512 * 4);  // split-K partials
  (void)ws_size; (void)in_sizes; (void)n_in; (void)out_size;

  // weight prep
  transW<<<dim3(16, 16, L_), dim3(32, 8), 0, stream>>>(Wq, qkvT,             512, 512, 512L * 512, 1536L * 512);
  transW<<<dim3(16, 16, L_), dim3(32, 8), 0, stream>>>(Wk, qkvT + 512 * 512, 512, 512, 512L * 512, 1536L * 512);
  transW<<<dim3(16, 16, L_), dim3(32, 8), 0, stream>>>(Wv, qkvT + 1024 * 512,512, 512, 512L * 512, 1536L * 512);
  transW<<<dim3(16, 16, L_), dim3(32, 8), 0, stream>>>(Wo, WoT,              512, 512, 512L * 512, 512L * 512);
  transW<<<dim3(64, 16, L_), dim3(32, 8), 0, stream>>>(W1, W1T,  512, 2048, 512L * 2048, 2048L * 512);
  transW<<<dim3(16, 64, L_), dim3(32, 8), 0, stream>>>(W2, W2T, 2048,  512, 2048L * 512, 512L * 2048);
  transW<<<dim3(1000, 16, 1), dim3(32, 8), 0, stream>>>(Wout, WoutT, 512, V_, 0, 0);
  bias_cat_kernel<<<36, 256, 0, stream>>>(bq, bk, bv, bqkv);

  // embed + ln1(layer 0)
  embed_ln_kernel<<<TOKENS, 256, 0, stream>>>(x, tok, pos, ln1s, ln1b, h, y);

  for (int l = 0; l < L_; ++l) {
    gemm_bt<1, 0, 0><<<dim3(12, 32), 256, 0, stream>>>(
        y, qkvT + (size_t)l * 1536 * 512, bqkv + l * 1536, nullptr, qkv, TOKENS, 1536, 512, 1536);
    attn_kernel<<<dim3(32, 16), 256, 0, stream>>>(qkv, obuf);
    // Wo projection: split-K=2 (256 wgs), partials -> h += .. + bo, then ln2
    gemm_bt_sk<<<dim3(4, 32, 2), 256, 0, stream>>>(
        obuf, WoT + (size_t)l * 512 * 512, part, TOKENS, 512, 512, 256);
    resid_ln_kernel<2, 1><<<TOKENS, 256, 0, stream>>>(
        part, bo + l * 512, h, ln2s + l * 512, ln2b + l * 512, y);
    gemm_bt<1, 0, 1><<<dim3(16, 32), 256, 0, stream>>>(
        y, W1T + (size_t)l * 2048 * 512, b1 + l * 2048, nullptr, ff, TOKENS, 2048, 512, 2048);
    // FF2: split-K=4 (512 wgs), partials -> h += .. + b2, then ln1(l+1) or bf16 copy
    gemm_bt_sk<<<dim3(4, 32, 4), 256, 0, stream>>>(
        ff, W2T + (size_t)l * 512 * 2048, part, TOKENS, 512, 2048, 512);
    if (l < L_ - 1)
      resid_ln_kernel<4, 1><<<TOKENS, 256, 0, stream>>>(
          part, b2 + l * 512, h, ln1s + (l + 1) * 512, ln1b + (l + 1) * 512, y);
    else
      resid_ln_kernel<4, 0><<<TOKENS, 256, 0, stream>>>(
          part, b2 + l * 512, h, nullptr, nullptr, hb);
  }

  gemm_bt<0, 0, 0><<<dim3(250, 32), 256, 0, stream>>>(
      hb, WoutT, bout, nullptr, (float*)d_out, TOKENS, V_, 512, V_);
}

// Round 2
// 1836.498 us; speedup vs baseline: 1.1964x; 1.0076x over previous
//
#include <hip/hip_runtime.h>
#include <cstdint>
#include <cstddef>

#define TOKENS 4096
#define E_ 512
#define T_ 2048
#define H_ 8
#define L_ 6
#define FF_ 2048
#define V_ 32000

typedef unsigned short u16;
typedef __attribute__((ext_vector_type(8))) short short8;
typedef __attribute__((ext_vector_type(4))) float f32x4;

__device__ __forceinline__ u16 f2b(float f) {
  union { float f; unsigned u; } x; x.f = f;
  unsigned r = x.u + 0x7fffu + ((x.u >> 16) & 1u);
  return (u16)(r >> 16);
}

// async 16B/lane global->LDS. lds ptr must be wave-uniform; HW scatters lane i to l + i*16.
__device__ __forceinline__ void gload_lds16(const void* g, void* l) {
  __builtin_amdgcn_global_load_lds((__attribute__((address_space(1))) void*)(uintptr_t)g,
                                   (__attribute__((address_space(3))) void*)l, 16, 0, 0);
}

// ---------------------------------------------------------------------------
// GEMM: C[M,N] = A[M,K](bf16) * BT[N,K](bf16)^T + bias, optional +resid / relu
// 128x128 tile, BK=32, 256 threads (4 waves, 2x2 of 64x64).
// 2-phase double-buffered pipeline (T3 minimum recipe): STAGE(t+1) issued
// BEFORE ds_read+MFMA of tile t; one __syncthreads per K-step. Load latency
// hides under compute — matters because these GEMMs run at 1-2 blocks/CU.
// ---------------------------------------------------------------------------
template<int BF16OUT, int RESID, int RELU>
__global__ __launch_bounds__(256) void gemm_bt(
    const u16* __restrict__ A, const u16* __restrict__ BT,
    const float* __restrict__ bias, const float* __restrict__ resid,
    void* __restrict__ outp, int M, int N, int K, int ldc)
{
  __shared__ u16 a_sm[2][128 * 32];
  __shared__ u16 b_sm[2][128 * 32];
  const int tid  = threadIdx.x;
  const int wave = tid >> 6;
  const int lane = tid & 63;
  const int l16  = lane & 15;
  const int quad = lane >> 4;
  const int bm = blockIdx.y << 7;
  const int bn = blockIdx.x << 7;
  const int wr = (wave >> 1) << 6;
  const int wc = (wave & 1) << 6;

  const int srow = tid >> 2;          // 0..63
  const int soff = (tid & 3) << 3;    // element offset in 32-wide K slab
  const u16* ag0 = A  + (size_t)(bm + srow) * K + soff;
  const u16* ag1 = A  + (size_t)(bm + 64 + srow) * K + soff;
  const u16* bg0 = BT + (size_t)(bn + srow) * K + soff;
  const u16* bg1 = BT + (size_t)(bn + 64 + srow) * K + soff;

  auto stage = [&](int buf, int k0) {
    gload_lds16(ag0 + k0, a_sm[buf] + wave * 512);
    gload_lds16(ag1 + k0, a_sm[buf] + 2048 + wave * 512);
    gload_lds16(bg0 + k0, b_sm[buf] + wave * 512);
    gload_lds16(bg1 + k0, b_sm[buf] + 2048 + wave * 512);
  };

  f32x4 acc[4][4] = {};
  const int ksteps = K >> 5;
  stage(0, 0);
  int cur = 0;
  for (int t = 0; t < ksteps; ++t) {
    __syncthreads();                       // buf[cur] staged; prior reads of buf[cur^1] done
    if (t + 1 < ksteps) stage(cur ^ 1, (t + 1) << 5);  // prefetch hides under compute
    short8 af[4], bf[4];
#pragma unroll
    for (int mt = 0; mt < 4; ++mt)
      af[mt] = *(const short8*)&a_sm[cur][(wr + mt * 16 + l16) * 32 + quad * 8];
#pragma unroll
    for (int nt = 0; nt < 4; ++nt)
      bf[nt] = *(const short8*)&b_sm[cur][(wc + nt * 16 + l16) * 32 + quad * 8];
#pragma unroll
    for (int mt = 0; mt < 4; ++mt)
#pragma unroll
      for (int nt = 0; nt < 4; ++nt)
        acc[mt][nt] = __builtin_amdgcn_mfma_f32_16x16x32_bf16(af[mt], bf[nt], acc[mt][nt], 0, 0, 0);
    cur ^= 1;
  }

#pragma unroll
  for (int mt = 0; mt < 4; ++mt) {
#pragma unroll
    for (int nt = 0; nt < 4; ++nt) {
      const int cg = bn + wc + nt * 16 + l16;
      const int rg = bm + wr + mt * 16 + quad * 4;
      const float bv = bias[cg];
#pragma unroll
      for (int i = 0; i < 4; ++i) {
        float v = acc[mt][nt][i] + bv;
        size_t idx = (size_t)(rg + i) * ldc + cg;
        if (RESID) v += resid[idx];
        if (RELU)  v = fmaxf(v, 0.f);
        if (BF16OUT) ((u16*)outp)[idx] = f2b(v);
        else         ((float*)outp)[idx] = v;
      }
    }
  }
}

// ---------------------------------------------------------------------------
// Split-K GEMM partial: part[z][M][N] = A[:, z*kLen:(z+1)*kLen] * BT^T chunk.
// Same 2-phase pipeline. fp32 out. lda = row stride of BOTH A and BT.
// ---------------------------------------------------------------------------
__global__ __launch_bounds__(256) void gemm_bt_sk(
    const u16* __restrict__ A, const u16* __restrict__ BT,
    float* __restrict__ part, int M, int N, int lda, int kLen)
{
  __shared__ u16 a_sm[2][128 * 32];
  __shared__ u16 b_sm[2][128 * 32];
  const int tid  = threadIdx.x;
  const int wave = tid >> 6;
  const int lane = tid & 63;
  const int l16  = lane & 15;
  const int quad = lane >> 4;
  const int bm = blockIdx.y << 7;
  const int bn = blockIdx.x << 7;
  const int wr = (wave >> 1) << 6;
  const int wc = (wave & 1) << 6;

  const u16* Ab = A  + (size_t)blockIdx.z * kLen;
  const u16* Bb = BT + (size_t)blockIdx.z * kLen;

  const int srow = tid >> 2;
  const int soff = (tid & 3) << 3;
  const u16* ag0 = Ab + (size_t)(bm + srow) * lda + soff;
  const u16* ag1 = Ab + (size_t)(bm + 64 + srow) * lda + soff;
  const u16* bg0 = Bb + (size_t)(bn + srow) * lda + soff;
  const u16* bg1 = Bb + (size_t)(bn + 64 + srow) * lda + soff;

  auto stage = [&](int buf, int k0) {
    gload_lds16(ag0 + k0, a_sm[buf] + wave * 512);
    gload_lds16(ag1 + k0, a_sm[buf] + 2048 + wave * 512);
    gload_lds16(bg0 + k0, b_sm[buf] + wave * 512);
    gload_lds16(bg1 + k0, b_sm[buf] + 2048 + wave * 512);
  };

  f32x4 acc[4][4] = {};
  const int ksteps = kLen >> 5;
  stage(0, 0);
  int cur = 0;
  for (int t = 0; t < ksteps; ++t) {
    __syncthreads();
    if (t + 1 < ksteps) stage(cur ^ 1, (t + 1) << 5);
    short8 af[4], bf[4];
#pragma unroll
    for (int mt = 0; mt < 4; ++mt)
      af[mt] = *(const short8*)&a_sm[cur][(wr + mt * 16 + l16) * 32 + quad * 8];
#pragma unroll
    for (int nt = 0; nt < 4; ++nt)
      bf[nt] = *(const short8*)&b_sm[cur][(wc + nt * 16 + l16) * 32 + quad * 8];
#pragma unroll
    for (int mt = 0; mt < 4; ++mt)
#pragma unroll
      for (int nt = 0; nt < 4; ++nt)
        acc[mt][nt] = __builtin_amdgcn_mfma_f32_16x16x32_bf16(af[mt], bf[nt], acc[mt][nt], 0, 0, 0);
    cur ^= 1;
  }

  float* out = part + (size_t)blockIdx.z * M * N;
#pragma unroll
  for (int mt = 0; mt < 4; ++mt) {
#pragma unroll
    for (int nt = 0; nt < 4; ++nt) {
      const int cg = bn + wc + nt * 16 + l16;
      const int rg = bm + wr + mt * 16 + quad * 4;
#pragma unroll
      for (int i = 0; i < 4; ++i)
        out[(size_t)(rg + i) * N + cg] = acc[mt][nt][i];
    }
  }
}

// ---------------------------------------------------------------------------
// Flash-style causal attention, KVBLK=64, T2 XOR-swizzled LDS, 2-phase
// double-buffered K/V pipeline: per tile, ONE barrier; prefetch of K(kt+1)
// (async LDS) + V(kt+1) (to regs) is issued right after the barrier and its
// latency hides under tile kt's QK^T/softmax/PV; vT(kt+1) is written to LDS
// after compute. All LDS reads use chunk ^= (row&7) swizzle; K staging uses
// the inverse swizzle on the per-lane GLOBAL source address (rule #21).
// ---------------------------------------------------------------------------
__global__ __launch_bounds__(256) void attn_kernel(const u16* __restrict__ qkv,
                                                   u16* __restrict__ o)
{
  __shared__ u16 k_sm[2][64 * 64];    // [key][d], swizzled
  __shared__ u16 vT_sm[2][64 * 64];   // [d][key], swizzled
  __shared__ u16 p_sm[4 * 16 * 64];   // per-wave P [qrow][key], swizzled
  const int tid  = threadIdx.x;
  const int wave = tid >> 6;
  const int lane = tid & 63;
  const int l16  = lane & 15;
  const int quad = lane >> 4;
  const int j  = blockIdx.x;                 // q tile of 64 rows
  const int bh = blockIdx.y;
  const int b  = bh >> 3, h = bh & 7;
  const size_t base = (size_t)b * T_ * 1536;

  // Q fragments (A-layout): rows j*64 + wave*16 + l16, k = half*32 + quad*8
  const int qrow = j * 64 + wave * 16 + l16;
  short8 aq[2];
#pragma unroll
  for (int half = 0; half < 2; ++half)
    aq[half] = *(const short8*)&qkv[base + (size_t)qrow * 1536 + h * 64 + half * 32 + quad * 8];

  f32x4 oacc[4] = {};
  float m_i[4] = {-INFINITY, -INFINITY, -INFINITY, -INFINITY};
  float l_i[4] = {0.f, 0.f, 0.f, 0.f};

  // pre-swizzled global source column offset for K staging
  const int ksrc = ((tid & 7) ^ ((tid >> 3) & 7)) * 8;
  auto stageK = [&](int kt, int buf) {
    gload_lds16(qkv + base + (size_t)(kt * 64 + (tid >> 3)) * 1536 + 512 + h * 64 + ksrc,
                k_sm[buf] + wave * 512);
    gload_lds16(qkv + base + (size_t)(kt * 64 + 32 + (tid >> 3)) * 1536 + 512 + h * 64 + ksrc,
                k_sm[buf] + 2048 + wave * 512);
  };
  const int vt = tid >> 2, vd0 = (tid & 3) * 16;   // key, d-offset for V loads
  auto loadV = [&](int kt, short8* vr) {
    const u16* vp = &qkv[base + (size_t)(kt * 64 + vt) * 1536 + 1024 + h * 64 + vd0];
    vr[0] = *(const short8*)vp;
    vr[1] = *(const short8*)(vp + 8);
  };
  auto writeV = [&](int buf, const short8* vr) {
#pragma unroll
    for (int i = 0; i < 8; ++i) vT_sm[buf][(vd0 + i) * 64 + (vt ^ (i << 3))] = (u16)vr[0][i];
#pragma unroll
    for (int i = 0; i < 8; ++i) vT_sm[buf][(vd0 + 8 + i) * 64 + (vt ^ (i << 3))] = (u16)vr[1][i];
  };

  const int nkt = j + 1;
  short8 vr[2], vrn[2];
  stageK(0, 0);
  loadV(0, vr);
  writeV(0, vr);               // vT[0] ready before first barrier
  int cur = 0;
  for (int kt = 0; kt < nkt; ++kt) {
    __syncthreads();           // k_sm[cur] staged + vT[cur] visible; prior reads of buf^1 done
    if (kt + 1 < nkt) { stageK(kt + 1, cur ^ 1); loadV(kt + 1, vrn); }

    // S = Q K^T (four 16x16 col-tiles over 64 keys)
    f32x4 s[4] = {};
#pragma unroll
    for (int nt = 0; nt < 4; ++nt)
#pragma unroll
      for (int half = 0; half < 2; ++half) {
        short8 bk = *(const short8*)&k_sm[cur][(nt * 16 + l16) * 64 +
                                              (((half * 4 + quad) ^ (l16 & 7)) << 3)];
        s[nt] = __builtin_amdgcn_mfma_f32_16x16x32_bf16(aq[half], bk, s[nt], 0, 0, 0);
      }
    // scale + causal mask
#pragma unroll
    for (int nt = 0; nt < 4; ++nt)
#pragma unroll
      for (int i = 0; i < 4; ++i) {
        const int col = kt * 64 + nt * 16 + l16;
        const int row = j * 64 + wave * 16 + quad * 4 + i;
        float sv = s[nt][i] * 0.125f;
        s[nt][i] = (col <= row) ? sv : -INFINITY;
      }
    // online softmax: row stats across the 16 lanes of each quad
    float rm[4], mn[4], alpha[4], rs[4], p[4][4];
#pragma unroll
    for (int i = 0; i < 4; ++i)
      rm[i] = fmaxf(fmaxf(s[0][i], s[1][i]), fmaxf(s[2][i], s[3][i]));
#pragma unroll
    for (int off = 1; off < 16; off <<= 1)
#pragma unroll
      for (int i = 0; i < 4; ++i) rm[i] = fmaxf(rm[i], __shfl_xor(rm[i], off));
#pragma unroll
    for (int i = 0; i < 4; ++i) {
      mn[i] = fmaxf(m_i[i], rm[i]);
      alpha[i] = __expf(m_i[i] - mn[i]);
      m_i[i] = mn[i];
#pragma unroll
      for (int nt = 0; nt < 4; ++nt) p[nt][i] = __expf(s[nt][i] - mn[i]);
      rs[i] = (p[0][i] + p[1][i]) + (p[2][i] + p[3][i]);
    }
#pragma unroll
    for (int off = 1; off < 16; off <<= 1)
#pragma unroll
      for (int i = 0; i < 4; ++i) rs[i] += __shfl_xor(rs[i], off);
#pragma unroll
    for (int i = 0; i < 4; ++i) l_i[i] = l_i[i] * alpha[i] + rs[i];
#pragma unroll
    for (int nt = 0; nt < 4; ++nt)
#pragma unroll
      for (int i = 0; i < 4; ++i) oacc[nt][i] *= alpha[i];
    // P: C-layout -> LDS (swizzled) -> A-layout (wave-private buffer)
    u16* pw = p_sm + wave * 1024;
#pragma unroll
    for (int i = 0; i < 4; ++i) {
      const int pr = quad * 4 + i;
#pragma unroll
      for (int nt = 0; nt < 4; ++nt)
        pw[pr * 64 + ((nt * 16 + l16) ^ ((pr & 7) << 3))] = f2b(p[nt][i]);
    }
    asm volatile("s_waitcnt lgkmcnt(0)" ::: "memory");
    short8 pf[2];
#pragma unroll
    for (int kh = 0; kh < 2; ++kh)
      pf[kh] = *(const short8*)&pw[l16 * 64 + (((kh * 4 + quad) ^ (l16 & 7)) << 3)];
#pragma unroll
    for (int nt = 0; nt < 4; ++nt)
#pragma unroll
      for (int kh = 0; kh < 2; ++kh) {
        short8 bv = *(const short8*)&vT_sm[cur][(nt * 16 + l16) * 64 +
                                               (((kh * 4 + quad) ^ (l16 & 7)) << 3)];
        oacc[nt] = __builtin_amdgcn_mfma_f32_16x16x32_bf16(pf[kh], bv, oacc[nt], 0, 0, 0);
      }

    if (kt + 1 < nkt) writeV(cur ^ 1, vrn);  // vT for next tile; visible after next barrier
    cur ^= 1;
  }
  // epilogue: O / l
#pragma unroll
  for (int nt = 0; nt < 4; ++nt)
#pragma unroll
    for (int i = 0; i < 4; ++i) {
      const int row = j * 64 + wave * 16 + quad * 4 + i;
      const float ov = oacc[nt][i] / l_i[i];
      o[(size_t)(b * T_ + row) * 512 + h * 64 + nt * 16 + l16] = f2b(ov);
    }
}

// ---------------------------------------------------------------------------
// Row LN helper: hv = this thread's 2 elems of a 512-row; writes bf16x2 to yrow.
// ---------------------------------------------------------------------------
__device__ __forceinline__ void ln_emit(float2 hv, const float* __restrict__ sc,
                                        const float* __restrict__ bi, int tid,
                                        unsigned* __restrict__ yrow)
{
  float s = hv.x + hv.y;
  float q = hv.x * hv.x + hv.y * hv.y;
  for (int off = 32; off; off >>= 1) { s += __shfl_down(s, off); q += __shfl_down(q, off); }
  __shared__ float red[8];
  const int wave = tid >> 6, lane = tid & 63;
  if (!lane) { red[wave] = s; red[4 + wave] = q; }
  __syncthreads();
  if (tid == 0) {
    float ts = 0, tq = 0;
    for (int w = 0; w < 4; ++w) { ts += red[w]; tq += red[4 + w]; }
    red[0] = ts; red[4] = tq;
  }
  __syncthreads();
  const float mu = red[0] * (1.f / 512.f);
  const float var = red[4] * (1.f / 512.f) - mu * mu;
  const float rstd = rsqrtf(var + 1e-5f);
  const float y0 = (hv.x - mu) * rstd * sc[tid * 2]     + bi[tid * 2];
  const float y1 = (hv.y - mu) * rstd * sc[tid * 2 + 1] + bi[tid * 2 + 1];
  yrow[tid] = ((unsigned)f2b(y1) << 16) | (unsigned)f2b(y0);
}

// ---------------------------------------------------------------------------
// Split-K reduce + residual + bias into h, fused with the NEXT op's LN (or a
// plain bf16 copy when DOLN=0). Row per block, 256 threads, float2/thread.
// ---------------------------------------------------------------------------
template<int NS, int DOLN>
__global__ __launch_bounds__(256) void resid_ln_kernel(
    const float* __restrict__ part, const float* __restrict__ bias,
    float* __restrict__ h, const float* __restrict__ sc,
    const float* __restrict__ bi, u16* __restrict__ y)
{
  const int row = blockIdx.x, tid = threadIdx.x;
  float2 hv = ((const float2*)(h + (size_t)row * 512))[tid];
  const float2 bv = ((const float2*)bias)[tid];
#pragma unroll
  for (int s = 0; s < NS; ++s) {
    const float2 pv = ((const float2*)(part + ((size_t)s * TOKENS + row) * 512))[tid];
    hv.x += pv.x; hv.y += pv.y;
  }
  hv.x += bv.x; hv.y += bv.y;
  ((float2*)(h + (size_t)row * 512))[tid] = hv;
  if (DOLN)
    ln_emit(hv, sc, bi, tid, (unsigned*)(y + (size_t)row * 512));
  else
    ((unsigned*)y)[(size_t)row * 256 + tid] = ((unsigned)f2b(hv.y) << 16) | (unsigned)f2b(hv.x);
}

// ---------------------------------------------------------------------------
// Embedding fused with ln1(layer 0): h[row] = tok_emb[x]+pos_emb, y = LN(h).
// ---------------------------------------------------------------------------
__global__ __launch_bounds__(256) void embed_ln_kernel(const int* __restrict__ x,
                                                       const float* __restrict__ tok,
                                                       const float* __restrict__ pos,
                                                       const float* __restrict__ sc,
                                                       const float* __restrict__ bi,
                                                       float* __restrict__ h,
                                                       u16* __restrict__ y)
{
  const int row = blockIdx.x, tid = threadIdx.x;
  const int t = row & (T_ - 1);
  const int tk = x[row];
  const float2 a = ((const float2*)tok)[(size_t)tk * 256 + tid];
  const float2 p = ((const float2*)pos)[(size_t)t * 256 + tid];
  float2 hv = make_float2(a.x + p.x, a.y + p.y);
  ((float2*)(h + (size_t)row * 512))[tid] = hv;
  ln_emit(hv, sc, bi, tid, (unsigned*)(y + (size_t)row * 512));
}

// ---------------------------------------------------------------------------
// Weight transpose + fp32->bf16: src [K][N] (layer stride sStr) -> dst [N][K]
// block (32,8), 32x32 tiles via padded LDS.
// ---------------------------------------------------------------------------
__global__ void transW(const float* __restrict__ src, u16* __restrict__ dst,
                       int K, int N, long sStr, long dStr)
{
  __shared__ float tile[32][33];
  const int l = blockIdx.z;
  const float* S = src + (size_t)l * sStr;
  u16* D = dst + (size_t)l * dStr;
  const int n0 = blockIdx.x * 32, k0 = blockIdx.y * 32;
  const int tx = threadIdx.x, ty = threadIdx.y;
#pragma unroll
  for (int i = 0; i < 4; ++i)
    tile[ty + 8 * i][tx] = S[(size_t)(k0 + ty + 8 * i) * N + n0 + tx];
  __syncthreads();
#pragma unroll
  for (int i = 0; i < 4; ++i)
    D[(size_t)(n0 + ty + 8 * i) * K + k0 + tx] = f2b(tile[tx][ty + 8 * i]);
}

__global__ __launch_bounds__(256) void bias_cat_kernel(const float* __restrict__ bq,
                                                       const float* __restrict__ bk,
                                                       const float* __restrict__ bv,
                                                       float* __restrict__ o)
{
  const int i = blockIdx.x * 256 + threadIdx.x;
  if (i >= L_ * 1536) return;
  const int l = i / 1536, c = i % 1536;
  float v = (c < 512) ? bq[l * 512 + c] : (c < 1024) ? bk[l * 512 + c - 512] : bv[l * 512 + c - 1024];
  o[i] = v;
}

// ---------------------------------------------------------------------------
extern "C" void kernel_launch(void* const* d_in, const int* in_sizes, int n_in,
                              void* d_out, int out_size, void* d_ws, size_t ws_size,
                              hipStream_t stream) {
  const int*   x     = (const int*)d_in[0];
  const float* tok   = (const float*)d_in[1];
  const float* pos   = (const float*)d_in[2];
  const float* Wq    = (const float*)d_in[3];
  const float* bq    = (const float*)d_in[4];
  const float* Wk    = (const float*)d_in[5];
  const float* bk    = (const float*)d_in[6];
  const float* Wv    = (const float*)d_in[7];
  const float* bv    = (const float*)d_in[8];
  const float* Wo    = (const float*)d_in[9];
  const float* bo    = (const float*)d_in[10];
  const float* ln1s  = (const float*)d_in[11];
  const float* ln1b  = (const float*)d_in[12];
  const float* ln2s  = (const float*)d_in[13];
  const float* ln2b  = (const float*)d_in[14];
  const float* W1    = (const float*)d_in[15];
  const float* b1    = (const float*)d_in[16];
  const float* W2    = (const float*)d_in[17];
  const float* b2    = (const float*)d_in[18];
  const float* Wout  = (const float*)d_in[19];
  const float* bout  = (const float*)d_in[20];

  char* ws = (char*)d_ws;
  size_t off = 0;
  auto alloc = [&](size_t bytes) { char* p = ws + off; off += (bytes + 255) & ~(size_t)255; return p; };
  u16*   qkvT  = (u16*)alloc((size_t)L_ * 1536 * 512 * 2);
  u16*   WoT   = (u16*)alloc((size_t)L_ * 512 * 512 * 2);
  u16*   W1T   = (u16*)alloc((size_t)L_ * 2048 * 512 * 2);
  u16*   W2T   = (u16*)alloc((size_t)L_ * 512 * 2048 * 2);
  u16*   WoutT = (u16*)alloc((size_t)V_ * 512 * 2);
  float* bqkv  = (float*)alloc((size_t)L_ * 1536 * 4);
  float* h     = (float*)alloc((size_t)TOKENS * 512 * 4);
  u16*   y     = (u16*)alloc((size_t)TOKENS * 512 * 2);
  u16*   qkv   = (u16*)alloc((size_t)TOKENS * 1536 * 2);
  u16*   obuf  = (u16*)alloc((size_t)TOKENS * 512 * 2);
  u16*   ff    = (u16*)alloc((size_t)TOKENS * 2048 * 2);
  u16*   hb    = (u16*)alloc((size_t)TOKENS * 512 * 2);
  float* part  = (float*)alloc((size_t)4 * TOKENS * 512 * 4);  // split-K partials
  (void)ws_size; (void)in_sizes; (void)n_in; (void)out_size;

  // weight prep
  transW<<<dim3(16, 16, L_), dim3(32, 8), 0, stream>>>(Wq, qkvT,             512, 512, 512L * 512, 1536L * 512);
  transW<<<dim3(16, 16, L_), dim3(32, 8), 0, stream>>>(Wk, qkvT + 512 * 512, 512, 512, 512L * 512, 1536L * 512);
  transW<<<dim3(16, 16, L_), dim3(32, 8), 0, stream>>>(Wv, qkvT + 1024 * 512,512, 512, 512L * 512, 1536L * 512);
  transW<<<dim3(16, 16, L_), dim3(32, 8), 0, stream>>>(Wo, WoT,              512, 512, 512L * 512, 512L * 512);
  transW<<<dim3(64, 16, L_), dim3(32, 8), 0, stream>>>(W1, W1T,  512, 2048, 512L * 2048, 2048L * 512);
  transW<<<dim3(16, 64, L_), dim3(32, 8), 0, stream>>>(W2, W2T, 2048,  512, 2048L * 512, 512L * 2048);
  transW<<<dim3(1000, 16, 1), dim3(32, 8), 0, stream>>>(Wout, WoutT, 512, V_, 0, 0);
  bias_cat_kernel<<<36, 256, 0, stream>>>(bq, bk, bv, bqkv);

  // embed + ln1(layer 0)
  embed_ln_kernel<<<TOKENS, 256, 0, stream>>>(x, tok, pos, ln1s, ln1b, h, y);

  for (int l = 0; l < L_; ++l) {
    gemm_bt<1, 0, 0><<<dim3(12, 32), 256, 0, stream>>>(
        y, qkvT + (size_t)l * 1536 * 512, bqkv + l * 1536, nullptr, qkv, TOKENS, 1536, 512, 1536);
    attn_kernel<<<dim3(32, 16), 256, 0, stream>>>(qkv, obuf);
    // Wo projection: split-K=2 (256 wgs), partials -> h += .. + bo, then ln2
    gemm_bt_sk<<<dim3(4, 32, 2), 256, 0, stream>>>(
        obuf, WoT + (size_t)l * 512 * 512, part, TOKENS, 512, 512, 256);
    resid_ln_kernel<2, 1><<<TOKENS, 256, 0, stream>>>(
        part, bo + l * 512, h, ln2s + l * 512, ln2b + l * 512, y);
    gemm_bt<1, 0, 1><<<dim3(16, 32), 256, 0, stream>>>(
        y, W1T + (size_t)l * 2048 * 512, b1 + l * 2048, nullptr, ff, TOKENS, 2048, 512, 2048);
    // FF2: split-K=4 (512 wgs), partials -> h += .. + b2, then ln1(l+1) or bf16 copy
    gemm_bt_sk<<<dim3(4, 32, 4), 256, 0, stream>>>(
        ff, W2T + (size_t)l * 512 * 2048, part, TOKENS, 512, 2048, 512);
    if (l < L_ - 1)
      resid_ln_kernel<4, 1><<<TOKENS, 256, 0, stream>>>(
          part, b2 + l * 512, h, ln1s + (l + 1) * 512, ln1b + (l + 1) * 512, y);
    else
      resid_ln_kernel<4, 0><<<TOKENS, 256, 0, stream>>>(
          part, b2 + l * 512, h, nullptr, nullptr, hb);
  }

  gemm_bt<0, 0, 0><<<dim3(250, 32), 256, 0, stream>>>(
      hb, WoutT, bout, nullptr, (float*)d_out, TOKENS, V_, 512, V_);
}

// Round 3
// 1833.139 us; speedup vs baseline: 1.1986x; 1.0018x over previous
//
#include <hip/hip_runtime.h>
#include <cstdint>
#include <cstddef>

#define TOKENS 4096
#define E_ 512
#define T_ 2048
#define H_ 8
#define L_ 6
#define FF_ 2048
#define V_ 32000

typedef unsigned short u16;
typedef __attribute__((ext_vector_type(8))) short short8;
typedef __attribute__((ext_vector_type(4))) float f32x4;

__device__ __forceinline__ u16 f2b(float f) {
  union { float f; unsigned u; } x; x.f = f;
  unsigned r = x.u + 0x7fffu + ((x.u >> 16) & 1u);
  return (u16)(r >> 16);
}

// async 16B/lane global->LDS. lds ptr must be wave-uniform; HW scatters lane i to l + i*16.
__device__ __forceinline__ void gload_lds16(const void* g, void* l) {
  __builtin_amdgcn_global_load_lds((__attribute__((address_space(1))) void*)(uintptr_t)g,
                                   (__attribute__((address_space(3))) void*)l, 16, 0, 0);
}

// ---------------------------------------------------------------------------
// GEMM (128x128 tile): used only for the final vocab projection (8000 blocks).
// 2-phase double-buffered pipeline.
// ---------------------------------------------------------------------------
template<int BF16OUT, int RESID, int RELU>
__global__ __launch_bounds__(256) void gemm_bt(
    const u16* __restrict__ A, const u16* __restrict__ BT,
    const float* __restrict__ bias, const float* __restrict__ resid,
    void* __restrict__ outp, int M, int N, int K, int ldc)
{
  __shared__ u16 a_sm[2][128 * 32];
  __shared__ u16 b_sm[2][128 * 32];
  const int tid  = threadIdx.x;
  const int wave = tid >> 6;
  const int lane = tid & 63;
  const int l16  = lane & 15;
  const int quad = lane >> 4;
  const int bm = blockIdx.y << 7;
  const int bn = blockIdx.x << 7;
  const int wr = (wave >> 1) << 6;
  const int wc = (wave & 1) << 6;

  const int srow = tid >> 2;          // 0..63
  const int soff = (tid & 3) << 3;    // element offset in 32-wide K slab
  const u16* ag0 = A  + (size_t)(bm + srow) * K + soff;
  const u16* ag1 = A  + (size_t)(bm + 64 + srow) * K + soff;
  const u16* bg0 = BT + (size_t)(bn + srow) * K + soff;
  const u16* bg1 = BT + (size_t)(bn + 64 + srow) * K + soff;

  auto stage = [&](int buf, int k0) {
    gload_lds16(ag0 + k0, a_sm[buf] + wave * 512);
    gload_lds16(ag1 + k0, a_sm[buf] + 2048 + wave * 512);
    gload_lds16(bg0 + k0, b_sm[buf] + wave * 512);
    gload_lds16(bg1 + k0, b_sm[buf] + 2048 + wave * 512);
  };

  f32x4 acc[4][4] = {};
  const int ksteps = K >> 5;
  stage(0, 0);
  int cur = 0;
  for (int t = 0; t < ksteps; ++t) {
    __syncthreads();
    if (t + 1 < ksteps) stage(cur ^ 1, (t + 1) << 5);
    short8 af[4], bf[4];
#pragma unroll
    for (int mt = 0; mt < 4; ++mt)
      af[mt] = *(const short8*)&a_sm[cur][(wr + mt * 16 + l16) * 32 + quad * 8];
#pragma unroll
    for (int nt = 0; nt < 4; ++nt)
      bf[nt] = *(const short8*)&b_sm[cur][(wc + nt * 16 + l16) * 32 + quad * 8];
#pragma unroll
    for (int mt = 0; mt < 4; ++mt)
#pragma unroll
      for (int nt = 0; nt < 4; ++nt)
        acc[mt][nt] = __builtin_amdgcn_mfma_f32_16x16x32_bf16(af[mt], bf[nt], acc[mt][nt], 0, 0, 0);
    cur ^= 1;
  }

#pragma unroll
  for (int mt = 0; mt < 4; ++mt) {
#pragma unroll
    for (int nt = 0; nt < 4; ++nt) {
      const int cg = bn + wc + nt * 16 + l16;
      const int rg = bm + wr + mt * 16 + quad * 4;
      const float bv = bias[cg];
#pragma unroll
      for (int i = 0; i < 4; ++i) {
        float v = acc[mt][nt][i] + bv;
        size_t idx = (size_t)(rg + i) * ldc + cg;
        if (RESID) v += resid[idx];
        if (RELU)  v = fmaxf(v, 0.f);
        if (BF16OUT) ((u16*)outp)[idx] = f2b(v);
        else         ((float*)outp)[idx] = v;
      }
    }
  }
}

// ---------------------------------------------------------------------------
// GEMM, 64x128 tile: doubles block count for the small per-layer GEMMs so
// 3-4 blocks are resident per CU (m114 wave-TLP hides stage latency; m102
// shows the 128^2 structure needs >=3 blocks/CU to leave the ~2000cy/step
// serial regime). 4 waves = 2x2 of 32x64; acc 2x4; 3 gload_lds16/K-step.
// ---------------------------------------------------------------------------
template<int BF16OUT, int RELU>
__global__ __launch_bounds__(256) void gemm_bt64(
    const u16* __restrict__ A, const u16* __restrict__ BT,
    const float* __restrict__ bias, void* __restrict__ outp,
    int M, int N, int K, int ldc)
{
  __shared__ u16 a_sm[2][64 * 32];
  __shared__ u16 b_sm[2][128 * 32];
  const int tid  = threadIdx.x;
  const int wave = tid >> 6;
  const int lane = tid & 63;
  const int l16  = lane & 15;
  const int quad = lane >> 4;
  const int bm = blockIdx.y << 6;
  const int bn = blockIdx.x << 7;
  const int wr = (wave >> 1) << 5;    // 0 or 32
  const int wc = (wave & 1) << 6;     // 0 or 64

  const int srow = tid >> 2;          // 0..63
  const int soff = (tid & 3) << 3;
  const u16* ag  = A  + (size_t)(bm + srow) * K + soff;
  const u16* bg0 = BT + (size_t)(bn + srow) * K + soff;
  const u16* bg1 = BT + (size_t)(bn + 64 + srow) * K + soff;

  auto stage = [&](int buf, int k0) {
    gload_lds16(ag  + k0, a_sm[buf] + wave * 512);
    gload_lds16(bg0 + k0, b_sm[buf] + wave * 512);
    gload_lds16(bg1 + k0, b_sm[buf] + 2048 + wave * 512);
  };

  f32x4 acc[2][4] = {};
  const int ksteps = K >> 5;
  stage(0, 0);
  int cur = 0;
  for (int t = 0; t < ksteps; ++t) {
    __syncthreads();
    if (t + 1 < ksteps) stage(cur ^ 1, (t + 1) << 5);
    short8 af[2], bf[4];
#pragma unroll
    for (int mt = 0; mt < 2; ++mt)
      af[mt] = *(const short8*)&a_sm[cur][(wr + mt * 16 + l16) * 32 + quad * 8];
#pragma unroll
    for (int nt = 0; nt < 4; ++nt)
      bf[nt] = *(const short8*)&b_sm[cur][(wc + nt * 16 + l16) * 32 + quad * 8];
#pragma unroll
    for (int mt = 0; mt < 2; ++mt)
#pragma unroll
      for (int nt = 0; nt < 4; ++nt)
        acc[mt][nt] = __builtin_amdgcn_mfma_f32_16x16x32_bf16(af[mt], bf[nt], acc[mt][nt], 0, 0, 0);
    cur ^= 1;
  }

#pragma unroll
  for (int mt = 0; mt < 2; ++mt) {
#pragma unroll
    for (int nt = 0; nt < 4; ++nt) {
      const int cg = bn + wc + nt * 16 + l16;
      const int rg = bm + wr + mt * 16 + quad * 4;
      const float bv = bias[cg];
#pragma unroll
      for (int i = 0; i < 4; ++i) {
        float v = acc[mt][nt][i] + bv;
        size_t idx = (size_t)(rg + i) * ldc + cg;
        if (RELU)  v = fmaxf(v, 0.f);
        if (BF16OUT) ((u16*)outp)[idx] = f2b(v);
        else         ((float*)outp)[idx] = v;
      }
    }
  }
}

// ---------------------------------------------------------------------------
// Split-K GEMM partial, 64x128 tile: part[z][M][N] = A[:,z*kLen..] * BT^T.
// ---------------------------------------------------------------------------
__global__ __launch_bounds__(256) void gemm_sk64(
    const u16* __restrict__ A, const u16* __restrict__ BT,
    float* __restrict__ part, int M, int N, int lda, int kLen)
{
  __shared__ u16 a_sm[2][64 * 32];
  __shared__ u16 b_sm[2][128 * 32];
  const int tid  = threadIdx.x;
  const int wave = tid >> 6;
  const int lane = tid & 63;
  const int l16  = lane & 15;
  const int quad = lane >> 4;
  const int bm = blockIdx.y << 6;
  const int bn = blockIdx.x << 7;
  const int wr = (wave >> 1) << 5;
  const int wc = (wave & 1) << 6;

  const u16* Ab = A  + (size_t)blockIdx.z * kLen;
  const u16* Bb = BT + (size_t)blockIdx.z * kLen;

  const int srow = tid >> 2;
  const int soff = (tid & 3) << 3;
  const u16* ag  = Ab + (size_t)(bm + srow) * lda + soff;
  const u16* bg0 = Bb + (size_t)(bn + srow) * lda + soff;
  const u16* bg1 = Bb + (size_t)(bn + 64 + srow) * lda + soff;

  auto stage = [&](int buf, int k0) {
    gload_lds16(ag  + k0, a_sm[buf] + wave * 512);
    gload_lds16(bg0 + k0, b_sm[buf] + wave * 512);
    gload_lds16(bg1 + k0, b_sm[buf] + 2048 + wave * 512);
  };

  f32x4 acc[2][4] = {};
  const int ksteps = kLen >> 5;
  stage(0, 0);
  int cur = 0;
  for (int t = 0; t < ksteps; ++t) {
    __syncthreads();
    if (t + 1 < ksteps) stage(cur ^ 1, (t + 1) << 5);
    short8 af[2], bf[4];
#pragma unroll
    for (int mt = 0; mt < 2; ++mt)
      af[mt] = *(const short8*)&a_sm[cur][(wr + mt * 16 + l16) * 32 + quad * 8];
#pragma unroll
    for (int nt = 0; nt < 4; ++nt)
      bf[nt] = *(const short8*)&b_sm[cur][(wc + nt * 16 + l16) * 32 + quad * 8];
#pragma unroll
    for (int mt = 0; mt < 2; ++mt)
#pragma unroll
      for (int nt = 0; nt < 4; ++nt)
        acc[mt][nt] = __builtin_amdgcn_mfma_f32_16x16x32_bf16(af[mt], bf[nt], acc[mt][nt], 0, 0, 0);
    cur ^= 1;
  }

  float* out = part + (size_t)blockIdx.z * M * N;
#pragma unroll
  for (int mt = 0; mt < 2; ++mt) {
#pragma unroll
    for (int nt = 0; nt < 4; ++nt) {
      const int cg = bn + wc + nt * 16 + l16;
      const int rg = bm + wr + mt * 16 + quad * 4;
#pragma unroll
      for (int i = 0; i < 4; ++i)
        out[(size_t)(rg + i) * N + cg] = acc[mt][nt][i];
    }
  }
}

// ---------------------------------------------------------------------------
// Flash-style causal attention, KVBLK=64, T2 XOR-swizzled LDS, 2-phase
// double-buffered K/V pipeline (unchanged from round 1 — passing & verified).
// ---------------------------------------------------------------------------
__global__ __launch_bounds__(256) void attn_kernel(const u16* __restrict__ qkv,
                                                   u16* __restrict__ o)
{
  __shared__ u16 k_sm[2][64 * 64];    // [key][d], swizzled
  __shared__ u16 vT_sm[2][64 * 64];   // [d][key], swizzled
  __shared__ u16 p_sm[4 * 16 * 64];   // per-wave P [qrow][key], swizzled
  const int tid  = threadIdx.x;
  const int wave = tid >> 6;
  const int lane = tid & 63;
  const int l16  = lane & 15;
  const int quad = lane >> 4;
  const int j  = blockIdx.x;                 // q tile of 64 rows
  const int bh = blockIdx.y;
  const int b  = bh >> 3, h = bh & 7;
  const size_t base = (size_t)b * T_ * 1536;

  const int qrow = j * 64 + wave * 16 + l16;
  short8 aq[2];
#pragma unroll
  for (int half = 0; half < 2; ++half)
    aq[half] = *(const short8*)&qkv[base + (size_t)qrow * 1536 + h * 64 + half * 32 + quad * 8];

  f32x4 oacc[4] = {};
  float m_i[4] = {-INFINITY, -INFINITY, -INFINITY, -INFINITY};
  float l_i[4] = {0.f, 0.f, 0.f, 0.f};

  const int ksrc = ((tid & 7) ^ ((tid >> 3) & 7)) * 8;
  auto stageK = [&](int kt, int buf) {
    gload_lds16(qkv + base + (size_t)(kt * 64 + (tid >> 3)) * 1536 + 512 + h * 64 + ksrc,
                k_sm[buf] + wave * 512);
    gload_lds16(qkv + base + (size_t)(kt * 64 + 32 + (tid >> 3)) * 1536 + 512 + h * 64 + ksrc,
                k_sm[buf] + 2048 + wave * 512);
  };
  const int vt = tid >> 2, vd0 = (tid & 3) * 16;
  auto loadV = [&](int kt, short8* vr) {
    const u16* vp = &qkv[base + (size_t)(kt * 64 + vt) * 1536 + 1024 + h * 64 + vd0];
    vr[0] = *(const short8*)vp;
    vr[1] = *(const short8*)(vp + 8);
  };
  auto writeV = [&](int buf, const short8* vr) {
#pragma unroll
    for (int i = 0; i < 8; ++i) vT_sm[buf][(vd0 + i) * 64 + (vt ^ (i << 3))] = (u16)vr[0][i];
#pragma unroll
    for (int i = 0; i < 8; ++i) vT_sm[buf][(vd0 + 8 + i) * 64 + (vt ^ (i << 3))] = (u16)vr[1][i];
  };

  const int nkt = j + 1;
  short8 vr[2], vrn[2];
  stageK(0, 0);
  loadV(0, vr);
  writeV(0, vr);
  int cur = 0;
  for (int kt = 0; kt < nkt; ++kt) {
    __syncthreads();
    if (kt + 1 < nkt) { stageK(kt + 1, cur ^ 1); loadV(kt + 1, vrn); }

    f32x4 s[4] = {};
#pragma unroll
    for (int nt = 0; nt < 4; ++nt)
#pragma unroll
      for (int half = 0; half < 2; ++half) {
        short8 bk = *(const short8*)&k_sm[cur][(nt * 16 + l16) * 64 +
                                              (((half * 4 + quad) ^ (l16 & 7)) << 3)];
        s[nt] = __builtin_amdgcn_mfma_f32_16x16x32_bf16(aq[half], bk, s[nt], 0, 0, 0);
      }
#pragma unroll
    for (int nt = 0; nt < 4; ++nt)
#pragma unroll
      for (int i = 0; i < 4; ++i) {
        const int col = kt * 64 + nt * 16 + l16;
        const int row = j * 64 + wave * 16 + quad * 4 + i;
        float sv = s[nt][i] * 0.125f;
        s[nt][i] = (col <= row) ? sv : -INFINITY;
      }
    float rm[4], mn[4], alpha[4], rs[4], p[4][4];
#pragma unroll
    for (int i = 0; i < 4; ++i)
      rm[i] = fmaxf(fmaxf(s[0][i], s[1][i]), fmaxf(s[2][i], s[3][i]));
#pragma unroll
    for (int off = 1; off < 16; off <<= 1)
#pragma unroll
      for (int i = 0; i < 4; ++i) rm[i] = fmaxf(rm[i], __shfl_xor(rm[i], off));
#pragma unroll
    for (int i = 0; i < 4; ++i) {
      mn[i] = fmaxf(m_i[i], rm[i]);
      alpha[i] = __expf(m_i[i] - mn[i]);
      m_i[i] = mn[i];
#pragma unroll
      for (int nt = 0; nt < 4; ++nt) p[nt][i] = __expf(s[nt][i] - mn[i]);
      rs[i] = (p[0][i] + p[1][i]) + (p[2][i] + p[3][i]);
    }
#pragma unroll
    for (int off = 1; off < 16; off <<= 1)
#pragma unroll
      for (int i = 0; i < 4; ++i) rs[i] += __shfl_xor(rs[i], off);
#pragma unroll
    for (int i = 0; i < 4; ++i) l_i[i] = l_i[i] * alpha[i] + rs[i];
#pragma unroll
    for (int nt = 0; nt < 4; ++nt)
#pragma unroll
      for (int i = 0; i < 4; ++i) oacc[nt][i] *= alpha[i];
    u16* pw = p_sm + wave * 1024;
#pragma unroll
    for (int i = 0; i < 4; ++i) {
      const int pr = quad * 4 + i;
#pragma unroll
      for (int nt = 0; nt < 4; ++nt)
        pw[pr * 64 + ((nt * 16 + l16) ^ ((pr & 7) << 3))] = f2b(p[nt][i]);
    }
    asm volatile("s_waitcnt lgkmcnt(0)" ::: "memory");
    short8 pf[2];
#pragma unroll
    for (int kh = 0; kh < 2; ++kh)
      pf[kh] = *(const short8*)&pw[l16 * 64 + (((kh * 4 + quad) ^ (l16 & 7)) << 3)];
#pragma unroll
    for (int nt = 0; nt < 4; ++nt)
#pragma unroll
      for (int kh = 0; kh < 2; ++kh) {
        short8 bv = *(const short8*)&vT_sm[cur][(nt * 16 + l16) * 64 +
                                               (((kh * 4 + quad) ^ (l16 & 7)) << 3)];
        oacc[nt] = __builtin_amdgcn_mfma_f32_16x16x32_bf16(pf[kh], bv, oacc[nt], 0, 0, 0);
      }

    if (kt + 1 < nkt) writeV(cur ^ 1, vrn);
    cur ^= 1;
  }
#pragma unroll
  for (int nt = 0; nt < 4; ++nt)
#pragma unroll
    for (int i = 0; i < 4; ++i) {
      const int row = j * 64 + wave * 16 + quad * 4 + i;
      const float ov = oacc[nt][i] / l_i[i];
      o[(size_t)(b * T_ + row) * 512 + h * 64 + nt * 16 + l16] = f2b(ov);
    }
}

// ---------------------------------------------------------------------------
// Row LN helper: hv = this thread's 2 elems of a 512-row; writes bf16x2 to yrow.
// ---------------------------------------------------------------------------
__device__ __forceinline__ void ln_emit(float2 hv, const float* __restrict__ sc,
                                        const float* __restrict__ bi, int tid,
                                        unsigned* __restrict__ yrow)
{
  float s = hv.x + hv.y;
  float q = hv.x * hv.x + hv.y * hv.y;
  for (int off = 32; off; off >>= 1) { s += __shfl_down(s, off); q += __shfl_down(q, off); }
  __shared__ float red[8];
  const int wave = tid >> 6, lane = tid & 63;
  if (!lane) { red[wave] = s; red[4 + wave] = q; }
  __syncthreads();
  if (tid == 0) {
    float ts = 0, tq = 0;
    for (int w = 0; w < 4; ++w) { ts += red[w]; tq += red[4 + w]; }
    red[0] = ts; red[4] = tq;
  }
  __syncthreads();
  const float mu = red[0] * (1.f / 512.f);
  const float var = red[4] * (1.f / 512.f) - mu * mu;
  const float rstd = rsqrtf(var + 1e-5f);
  const float y0 = (hv.x - mu) * rstd * sc[tid * 2]     + bi[tid * 2];
  const float y1 = (hv.y - mu) * rstd * sc[tid * 2 + 1] + bi[tid * 2 + 1];
  yrow[tid] = ((unsigned)f2b(y1) << 16) | (unsigned)f2b(y0);
}

// ---------------------------------------------------------------------------
// Split-K reduce + residual + bias into h, fused with the NEXT op's LN (or a
// plain bf16 copy when DOLN=0). Row per block, 256 threads, float2/thread.
// ---------------------------------------------------------------------------
template<int NS, int DOLN>
__global__ __launch_bounds__(256) void resid_ln_kernel(
    const float* __restrict__ part, const float* __restrict__ bias,
    float* __restrict__ h, const float* __restrict__ sc,
    const float* __restrict__ bi, u16* __restrict__ y)
{
  const int row = blockIdx.x, tid = threadIdx.x;
  float2 hv = ((const float2*)(h + (size_t)row * 512))[tid];
  const float2 bv = ((const float2*)bias)[tid];
#pragma unroll
  for (int s = 0; s < NS; ++s) {
    const float2 pv = ((const float2*)(part + ((size_t)s * TOKENS + row) * 512))[tid];
    hv.x += pv.x; hv.y += pv.y;
  }
  hv.x += bv.x; hv.y += bv.y;
  ((float2*)(h + (size_t)row * 512))[tid] = hv;
  if (DOLN)
    ln_emit(hv, sc, bi, tid, (unsigned*)(y + (size_t)row * 512));
  else
    ((unsigned*)y)[(size_t)row * 256 + tid] = ((unsigned)f2b(hv.y) << 16) | (unsigned)f2b(hv.x);
}

// ---------------------------------------------------------------------------
// Embedding fused with ln1(layer 0): h[row] = tok_emb[x]+pos_emb, y = LN(h).
// ---------------------------------------------------------------------------
__global__ __launch_bounds__(256) void embed_ln_kernel(const int* __restrict__ x,
                                                       const float* __restrict__ tok,
                                                       const float* __restrict__ pos,
                                                       const float* __restrict__ sc,
                                                       const float* __restrict__ bi,
                                                       float* __restrict__ h,
                                                       u16* __restrict__ y)
{
  const int row = blockIdx.x, tid = threadIdx.x;
  const int t = row & (T_ - 1);
  const int tk = x[row];
  const float2 a = ((const float2*)tok)[(size_t)tk * 256 + tid];
  const float2 p = ((const float2*)pos)[(size_t)t * 256 + tid];
  float2 hv = make_float2(a.x + p.x, a.y + p.y);
  ((float2*)(h + (size_t)row * 512))[tid] = hv;
  ln_emit(hv, sc, bi, tid, (unsigned*)(y + (size_t)row * 512));
}

// ---------------------------------------------------------------------------
// Weight transpose + fp32->bf16: src [K][N] (layer stride sStr) -> dst [N][K]
// block (32,8), 32x32 tiles via padded LDS.
// ---------------------------------------------------------------------------
__global__ void transW(const float* __restrict__ src, u16* __restrict__ dst,
                       int K, int N, long sStr, long dStr)
{
  __shared__ float tile[32][33];
  const int l = blockIdx.z;
  const float* S = src + (size_t)l * sStr;
  u16* D = dst + (size_t)l * dStr;
  const int n0 = blockIdx.x * 32, k0 = blockIdx.y * 32;
  const int tx = threadIdx.x, ty = threadIdx.y;
#pragma unroll
  for (int i = 0; i < 4; ++i)
    tile[ty + 8 * i][tx] = S[(size_t)(k0 + ty + 8 * i) * N + n0 + tx];
  __syncthreads();
#pragma unroll
  for (int i = 0; i < 4; ++i)
    D[(size_t)(n0 + ty + 8 * i) * K + k0 + tx] = f2b(tile[tx][ty + 8 * i]);
}

__global__ __launch_bounds__(256) void bias_cat_kernel(const float* __restrict__ bq,
                                                       const float* __restrict__ bk,
                                                       const float* __restrict__ bv,
                                                       float* __restrict__ o)
{
  const int i = blockIdx.x * 256 + threadIdx.x;
  if (i >= L_ * 1536) return;
  const int l = i / 1536, c = i % 1536;
  float v = (c < 512) ? bq[l * 512 + c] : (c < 1024) ? bk[l * 512 + c - 512] : bv[l * 512 + c - 1024];
  o[i] = v;
}

// ---------------------------------------------------------------------------
extern "C" void kernel_launch(void* const* d_in, const int* in_sizes, int n_in,
                              void* d_out, int out_size, void* d_ws, size_t ws_size,
                              hipStream_t stream) {
  const int*   x     = (const int*)d_in[0];
  const float* tok   = (const float*)d_in[1];
  const float* pos   = (const float*)d_in[2];
  const float* Wq    = (const float*)d_in[3];
  const float* bq    = (const float*)d_in[4];
  const float* Wk    = (const float*)d_in[5];
  const float* bk    = (const float*)d_in[6];
  const float* Wv    = (const float*)d_in[7];
  const float* bv    = (const float*)d_in[8];
  const float* Wo    = (const float*)d_in[9];
  const float* bo    = (const float*)d_in[10];
  const float* ln1s  = (const float*)d_in[11];
  const float* ln1b  = (const float*)d_in[12];
  const float* ln2s  = (const float*)d_in[13];
  const float* ln2b  = (const float*)d_in[14];
  const float* W1    = (const float*)d_in[15];
  const float* b1    = (const float*)d_in[16];
  const float* W2    = (const float*)d_in[17];
  const float* b2    = (const float*)d_in[18];
  const float* Wout  = (const float*)d_in[19];
  const float* bout  = (const float*)d_in[20];

  char* ws = (char*)d_ws;
  size_t off = 0;
  auto alloc = [&](size_t bytes) { char* p = ws + off; off += (bytes + 255) & ~(size_t)255; return p; };
  u16*   qkvT  = (u16*)alloc((size_t)L_ * 1536 * 512 * 2);
  u16*   WoT   = (u16*)alloc((size_t)L_ * 512 * 512 * 2);
  u16*   W1T   = (u16*)alloc((size_t)L_ * 2048 * 512 * 2);
  u16*   W2T   = (u16*)alloc((size_t)L_ * 512 * 2048 * 2);
  u16*   WoutT = (u16*)alloc((size_t)V_ * 512 * 2);
  float* bqkv  = (float*)alloc((size_t)L_ * 1536 * 4);
  float* h     = (float*)alloc((size_t)TOKENS * 512 * 4);
  u16*   y     = (u16*)alloc((size_t)TOKENS * 512 * 2);
  u16*   qkv   = (u16*)alloc((size_t)TOKENS * 1536 * 2);
  u16*   obuf  = (u16*)alloc((size_t)TOKENS * 512 * 2);
  u16*   ff    = (u16*)alloc((size_t)TOKENS * 2048 * 2);
  u16*   hb    = (u16*)alloc((size_t)TOKENS * 512 * 2);
  float* part  = (float*)alloc((size_t)4 * TOKENS * 512 * 4);  // split-K partials
  (void)ws_size; (void)in_sizes; (void)n_in; (void)out_size;

  // weight prep
  transW<<<dim3(16, 16, L_), dim3(32, 8), 0, stream>>>(Wq, qkvT,             512, 512, 512L * 512, 1536L * 512);
  transW<<<dim3(16, 16, L_), dim3(32, 8), 0, stream>>>(Wk, qkvT + 512 * 512, 512, 512, 512L * 512, 1536L * 512);
  transW<<<dim3(16, 16, L_), dim3(32, 8), 0, stream>>>(Wv, qkvT + 1024 * 512,512, 512, 512L * 512, 1536L * 512);
  transW<<<dim3(16, 16, L_), dim3(32, 8), 0, stream>>>(Wo, WoT,              512, 512, 512L * 512, 512L * 512);
  transW<<<dim3(64, 16, L_), dim3(32, 8), 0, stream>>>(W1, W1T,  512, 2048, 512L * 2048, 2048L * 512);
  transW<<<dim3(16, 64, L_), dim3(32, 8), 0, stream>>>(W2, W2T, 2048,  512, 2048L * 512, 512L * 2048);
  transW<<<dim3(1000, 16, 1), dim3(32, 8), 0, stream>>>(Wout, WoutT, 512, V_, 0, 0);
  bias_cat_kernel<<<36, 256, 0, stream>>>(bq, bk, bv, bqkv);

  // embed + ln1(layer 0)
  embed_ln_kernel<<<TOKENS, 256, 0, stream>>>(x, tok, pos, ln1s, ln1b, h, y);

  for (int l = 0; l < L_; ++l) {
    // QKV: 768 blocks (3/CU)
    gemm_bt64<1, 0><<<dim3(12, 64), 256, 0, stream>>>(
        y, qkvT + (size_t)l * 1536 * 512, bqkv + l * 1536, qkv, TOKENS, 1536, 512, 1536);
    attn_kernel<<<dim3(32, 16), 256, 0, stream>>>(qkv, obuf);
    // Wo projection: 64-tile + split-K=2 -> 512 blocks, kLen=256
    gemm_sk64<<<dim3(4, 64, 2), 256, 0, stream>>>(
        obuf, WoT + (size_t)l * 512 * 512, part, TOKENS, 512, 512, 256);
    resid_ln_kernel<2, 1><<<TOKENS, 256, 0, stream>>>(
        part, bo + l * 512, h, ln2s + l * 512, ln2b + l * 512, y);
    // FF1: 1024 blocks (4/CU)
    gemm_bt64<1, 1><<<dim3(16, 64), 256, 0, stream>>>(
        y, W1T + (size_t)l * 2048 * 512, b1 + l * 2048, ff, TOKENS, 2048, 512, 2048);
    // FF2: 64-tile + split-K=2 -> 512 blocks, kLen=1024
    gemm_sk64<<<dim3(4, 64, 2), 256, 0, stream>>>(
        ff, W2T + (size_t)l * 512 * 2048, part, TOKENS, 512, 2048, 1024);
    if (l < L_ - 1)
      resid_ln_kernel<2, 1><<<TOKENS, 256, 0, stream>>>(
          part, b2 + l * 512, h, ln1s + (l + 1) * 512, ln1b + (l + 1) * 512, y);
    else
      resid_ln_kernel<2, 0><<<TOKENS, 256, 0, stream>>>(
          part, b2 + l * 512, h, nullptr, nullptr, hb);
  }

  gemm_bt<0, 0, 0><<<dim3(250, 32), 256, 0, stream>>>(
      hb, WoutT, bout, nullptr, (float*)d_out, TOKENS, V_, 512, V_);
}